// Round 11
// baseline (38.035 us; speedup 1.0000x reference)
//
#include <hip/hip_runtime.h>
#include <cstddef>

#define HH   64
#define WW   64
#define HWSZ 4096
#define CIN  256

typedef __attribute__((ext_vector_type(4))) float f32x4;
typedef _Float16 f16x4_t __attribute__((ext_vector_type(4)));
typedef _Float16 f16x8_t __attribute__((ext_vector_type(8)));

// Fully fused, 2-row tiles, 2 blocks/CU target.
// Block = (b, ht, g): inner px = 128 (rows h0..h0+1), halo px = 256 (rows h0-1..h0+2, clamped).
// Phase A: [q;k](128ch) x halo(256px), K=256, fp16 MFMA, all-fp16 LDS (reg-staged).
// Phase A2: logits + softmax, 4 threads/px (16ch each), shfl_xor(16,32).
// Phase B: v(64ch) x halo(256px) -> vlds (overlays klds).
// Phase B2: PV + direct out write. No workspace at all.
__global__ __launch_bounds__(512, 4) void fused_kernel(
    const float* __restrict__ x,
    const float* __restrict__ wq, const float* __restrict__ bq,
    const float* __restrict__ wk, const float* __restrict__ bk,
    const float* __restrict__ wv, const float* __restrict__ bv,
    float* __restrict__ out)
{
    __shared__ __align__(16) char smem[57344];          // 56 KB -> 2 blocks/CU
    _Float16* As   = (_Float16*)smem;                   // [128][32] fp16  8 KB
    _Float16* Bs   = (_Float16*)(smem + 8192);          // [256][32] fp16 16 KB
    _Float16* qlds = (_Float16*)smem;                   // [128][64] 16 KB (overlays As+Bs)
    _Float16* klds = (_Float16*)(smem + 24576);         // [256][64] 32 KB (vlds overlays)

    const int t   = threadIdx.x;
    const int bx0 = blockIdx.x;
    const int bx  = (bx0 & 7) * 64 + (bx0 >> 3);        // 512 = 8*64 bijective XCD swizzle
    const int g   = bx & 3;
    const int ht  = (bx >> 2) & 31;
    const int b   = bx >> 7;
    const int h0  = ht * 2;

    const int l    = t & 63, wid = t >> 6;
    const int lrow = l & 15, grp = l >> 4;
    const int grp4 = grp * 4;
    const int swzr = (lrow >> 1) & 3;                   // frag-row k-oct swizzle
    const int wmA  = wid >> 2, wnA = wid & 3;           // phase A wave decomp (2m x 4n)

    const float* xb = x + (size_t)b * CIN * HWSZ;

    // ---- staging indices ----
    // A (W -> As[128][32] fp16): thread = (m = t>>2, koct = t&3)
    const int smA = t >> 2, skA = t & 3;
    const float* aqk = (smA < 64 ? wq + (size_t)(g * 64 + smA) * CIN
                                 : wk + (size_t)(g * 64 + smA - 64) * CIN) + skA * 8;
    const int awz = smA * 32 + ((skA ^ ((smA >> 1) & 3)) << 3);

    // A (v -> As[64][32], phase B, t<256): m = (t>>2)&63, koct = t&3
    const int mv = (t >> 2) & 63;
    const float* avv = wv + (size_t)(g * 64 + mv) * CIN + skA * 8;
    const int awzV = mv * 32 + ((skA ^ ((mv >> 1) & 3)) << 3);

    // B (x -> Bs[256][32] fp16): thread = (px0 = t&127 and px0+128, koct = t>>7)
    const int spx0 = t & 127, skB = t >> 7;
    const int spx1 = spx0 + 128;
    int sr0 = h0 - 1 + (spx0 >> 6); sr0 = sr0 < 0 ? 0 : sr0;     // halo rows 0,1
    int sr1 = h0 - 1 + (spx1 >> 6); sr1 = sr1 > 63 ? 63 : sr1;   // halo rows 2,3
    const float* bgp0 = xb + (size_t)(skB * 8) * HWSZ + sr0 * 64 + (spx0 & 63);
    const float* bgp1 = xb + (size_t)(skB * 8) * HWSZ + sr1 * 64 + (spx1 & 63);
    const int bwz0 = spx0 * 32 + ((skB ^ ((spx0 >> 1) & 3)) << 3);
    const int bwz1 = spx1 * 32 + ((skB ^ ((spx1 >> 1) & 3)) << 3);

    // =================== Phase A: [q;k] GEMM 128 x 256 ===================
    const float* biasA = wmA ? bk : bq;
    f32x4 accA[4][4];
    #pragma unroll
    for (int mi = 0; mi < 4; ++mi) {
        const f32x4 bb = *(const f32x4*)&biasA[g * 64 + mi * 16 + grp4];
        #pragma unroll
        for (int ni = 0; ni < 4; ++ni) accA[mi][ni] = bb;
    }

    for (int kt = 0; kt < 8; ++kt) {
        // issue global loads (overlap prior MFMA / barrier wait)
        const float4 A0 = *(const float4*)(aqk + kt * 32);
        const float4 A1 = *(const float4*)(aqk + kt * 32 + 4);
        float lb0[8], lb1[8];
        #pragma unroll
        for (int j = 0; j < 8; ++j) lb0[j] = bgp0[(size_t)(kt * 32 + j) * HWSZ];
        #pragma unroll
        for (int j = 0; j < 8; ++j) lb1[j] = bgp1[(size_t)(kt * 32 + j) * HWSZ];
        __syncthreads();                       // prev-step frag reads complete

        f16x8_t fa, f0, f1;
        const float* pA0 = (const float*)&A0;
        const float* pA1 = (const float*)&A1;
        #pragma unroll
        for (int j = 0; j < 4; ++j) { fa[j] = (_Float16)pA0[j]; fa[4 + j] = (_Float16)pA1[j]; }
        #pragma unroll
        for (int j = 0; j < 8; ++j) { f0[j] = (_Float16)lb0[j]; f1[j] = (_Float16)lb1[j]; }
        *(f16x8_t*)&As[awz]  = fa;
        *(f16x8_t*)&Bs[bwz0] = f0;
        *(f16x8_t*)&Bs[bwz1] = f1;
        __syncthreads();

        f16x8_t af[4], bf[4];
        #pragma unroll
        for (int mi = 0; mi < 4; ++mi)
            af[mi] = *(const f16x8_t*)&As[(wmA * 64 + mi * 16 + lrow) * 32 + ((grp ^ swzr) << 3)];
        #pragma unroll
        for (int ni = 0; ni < 4; ++ni)
            bf[ni] = *(const f16x8_t*)&Bs[(wnA * 64 + ni * 16 + lrow) * 32 + ((grp ^ swzr) << 3)];
        #pragma unroll
        for (int mi = 0; mi < 4; ++mi)
            #pragma unroll
            for (int ni = 0; ni < 4; ++ni)
                accA[mi][ni] = __builtin_amdgcn_mfma_f32_16x16x32_f16(
                    af[mi], bf[ni], accA[mi][ni], 0, 0, 0);
    }
    __syncthreads();   // all As/Bs reads done before qlds overlay writes

    // ---- A epilogue: q (inner px) -> qlds, k (all halo px) -> klds ----
    #pragma unroll
    for (int ni = 0; ni < 4; ++ni) {
        const int px  = wnA * 64 + ni * 16 + lrow;
        const int spx = px - 64;
        #pragma unroll
        for (int mi = 0; mi < 4; ++mi) {
            f16x4_t hv;
            #pragma unroll
            for (int j = 0; j < 4; ++j) hv[j] = (_Float16)accA[mi][ni][j];
            const int cb = mi * 2 + (grp >> 1), off = (grp & 1) * 4;
            if (wmA == 0) {
                if (spx >= 0 && spx < 128)
                    *(f16x4_t*)&qlds[spx * 64 + ((cb ^ (spx & 7)) << 3) + off] = hv;
            } else {
                *(f16x4_t*)&klds[px * 64 + ((cb ^ (px & 7)) << 3) + off] = hv;
            }
        }
    }
    __syncthreads();

    // =================== Phase A2: logits + softmax ===================
    const int pxi  = wid * 16 + lrow;        // inner px 0..127
    const int cq   = grp;                    // 16-ch chunk 0..3
    const int hq   = h0 + (pxi >> 6);
    const int wcol = pxi & 63;

    float qf[16];
    #pragma unroll
    for (int hh2 = 0; hh2 < 2; ++hh2) {
        const f16x8_t qv = *(const f16x8_t*)&qlds[pxi * 64 + (((2 * cq + hh2) ^ (pxi & 7)) << 3)];
        #pragma unroll
        for (int e = 0; e < 8; ++e) qf[hh2 * 8 + e] = (float)qv[e];
    }

    float lg[9];
    #pragma unroll
    for (int p = 0; p < 9; ++p) {
        const int dh = p / 3 - 1, dw = p % 3 - 1;
        const int h2 = hq + dh, w2 = wcol + dw;
        float part = 0.f;
        if (h2 >= 0 && h2 < HH && w2 >= 0 && w2 < WW) {
            const int hpx = pxi + 64 + dh * 64 + dw;
            #pragma unroll
            for (int hh2 = 0; hh2 < 2; ++hh2) {
                const f16x8_t kv = *(const f16x8_t*)&klds[hpx * 64 + (((2 * cq + hh2) ^ (hpx & 7)) << 3)];
                #pragma unroll
                for (int e = 0; e < 8; ++e) part += qf[hh2 * 8 + e] * (float)kv[e];
            }
        }
        part += __shfl_xor(part, 16, 64);
        part += __shfl_xor(part, 32, 64);
        lg[p] = part;
    }

    float mx = lg[0];
    #pragma unroll
    for (int p = 1; p < 9; ++p) mx = fmaxf(mx, lg[p]);
    float a[9];
    float sum = 0.f;
    #pragma unroll
    for (int p = 0; p < 9; ++p) { a[p] = __expf(lg[p] - mx); sum += a[p]; }
    const float inv = 1.f / sum;
    #pragma unroll
    for (int p = 0; p < 9; ++p) a[p] *= inv;
    __syncthreads();   // qlds (= As/Bs region) reads done before B staging

    // =================== Phase B: v GEMM 64 x 256 ===================
    f32x4 accB[4][2];
    #pragma unroll
    for (int mi = 0; mi < 4; ++mi) {
        const f32x4 bb = *(const f32x4*)&bv[g * 64 + mi * 16 + grp4];
        accB[mi][0] = bb; accB[mi][1] = bb;
    }

    for (int kt = 0; kt < 8; ++kt) {
        float4 V0, V1;
        if (t < 256) {
            V0 = *(const float4*)(avv + kt * 32);
            V1 = *(const float4*)(avv + kt * 32 + 4);
        }
        float lb0[8], lb1[8];
        #pragma unroll
        for (int j = 0; j < 8; ++j) lb0[j] = bgp0[(size_t)(kt * 32 + j) * HWSZ];
        #pragma unroll
        for (int j = 0; j < 8; ++j) lb1[j] = bgp1[(size_t)(kt * 32 + j) * HWSZ];
        __syncthreads();

        if (t < 256) {
            f16x8_t fv;
            const float* pV0 = (const float*)&V0;
            const float* pV1 = (const float*)&V1;
            #pragma unroll
            for (int j = 0; j < 4; ++j) { fv[j] = (_Float16)pV0[j]; fv[4 + j] = (_Float16)pV1[j]; }
            *(f16x8_t*)&As[awzV] = fv;
        }
        f16x8_t f0, f1;
        #pragma unroll
        for (int j = 0; j < 8; ++j) { f0[j] = (_Float16)lb0[j]; f1[j] = (_Float16)lb1[j]; }
        *(f16x8_t*)&Bs[bwz0] = f0;
        *(f16x8_t*)&Bs[bwz1] = f1;
        __syncthreads();

        f16x8_t af[4], bf2[2];
        #pragma unroll
        for (int mi = 0; mi < 4; ++mi)
            af[mi] = *(const f16x8_t*)&As[(mi * 16 + lrow) * 32 + ((grp ^ swzr) << 3)];
        #pragma unroll
        for (int ni = 0; ni < 2; ++ni)
            bf2[ni] = *(const f16x8_t*)&Bs[(wid * 32 + ni * 16 + lrow) * 32 + ((grp ^ swzr) << 3)];
        #pragma unroll
        for (int mi = 0; mi < 4; ++mi)
            #pragma unroll
            for (int ni = 0; ni < 2; ++ni)
                accB[mi][ni] = __builtin_amdgcn_mfma_f32_16x16x32_f16(
                    af[mi], bf2[ni], accB[mi][ni], 0, 0, 0);
    }

    // ---- B epilogue: v -> vlds (overlays klds; A2 k-reads long done) ----
    #pragma unroll
    for (int ni = 0; ni < 2; ++ni) {
        const int px = wid * 32 + ni * 16 + lrow;
        #pragma unroll
        for (int mi = 0; mi < 4; ++mi) {
            f16x4_t hv;
            #pragma unroll
            for (int j = 0; j < 4; ++j) hv[j] = (_Float16)accB[mi][ni][j];
            const int cb = mi * 2 + (grp >> 1), off = (grp & 1) * 4;
            *(f16x4_t*)&klds[px * 64 + ((cb ^ (px & 7)) << 3) + off] = hv;
        }
    }
    __syncthreads();

    // =================== Phase B2: PV + out write ===================
    float oacc[16];
    #pragma unroll
    for (int c = 0; c < 16; ++c) oacc[c] = 0.f;
    #pragma unroll
    for (int p = 0; p < 9; ++p) {
        const int dh = p / 3 - 1, dw = p % 3 - 1;
        const int h2 = hq + dh, w2 = wcol + dw;
        if (h2 < 0 || h2 >= HH || w2 < 0 || w2 >= WW) continue;
        const float ap = a[p];
        const int hpx = pxi + 64 + dh * 64 + dw;
        #pragma unroll
        for (int hh2 = 0; hh2 < 2; ++hh2) {
            const f16x8_t vv = *(const f16x8_t*)&klds[hpx * 64 + (((2 * cq + hh2) ^ (hpx & 7)) << 3)];
            #pragma unroll
            for (int e = 0; e < 8; ++e) oacc[hh2 * 8 + e] += ap * (float)vv[e];
        }
    }

    float* ob = out + ((size_t)(b * 256 + g * 64 + cq * 16)) * HWSZ + h0 * 64 + pxi;
    #pragma unroll
    for (int c = 0; c < 16; ++c) ob[(size_t)c * HWSZ] = oacc[c];
}

extern "C" void kernel_launch(void* const* d_in, const int* in_sizes, int n_in,
                              void* d_out, int out_size, void* d_ws, size_t ws_size,
                              hipStream_t stream) {
    const float* x  = (const float*)d_in[0];
    const float* wq = (const float*)d_in[1];
    const float* bq = (const float*)d_in[2];
    const float* wk = (const float*)d_in[3];
    const float* bk = (const float*)d_in[4];
    const float* wv = (const float*)d_in[5];
    const float* bv = (const float*)d_in[6];
    float* out = (float*)d_out;

    fused_kernel<<<dim3(512), 512, 0, stream>>>(x, wq, bq, wk, bk, wv, bv, out);
}

// Round 12
// 33.818 us; speedup vs baseline: 1.1247x; 1.1247x over previous
//
#include <hip/hip_runtime.h>
#include <cstddef>
#include <cstdint>

#define BDIM 4
#define HH   64
#define WW   64
#define NG   4
#define GD   64
#define HWSZ 4096
#define NTOT 16384          // BDIM*HWSZ
#define CIN  256

typedef __attribute__((ext_vector_type(4))) float f32x4;
typedef _Float16 f16x4_t __attribute__((ext_vector_type(4)));
typedef _Float16 f16x8_t __attribute__((ext_vector_type(8)));

__device__ __forceinline__ void lds_load16(const void* g, void* l) {
    __builtin_amdgcn_global_load_lds(
        (const __attribute__((address_space(1))) unsigned int*)g,
        (__attribute__((address_space(3))) unsigned int*)l, 16, 0, 0);
}

// ---------- fused QKV GEMM: fp32 in, fp16 MFMA, fp16 blocked out ----------
// D[768 x 16384] = W[768 x 256] * x[256 x 16384]. 128x128 tile, 4 waves,
// BK=32, 8 K-steps, 2-deep double buffer (issue-early / write-late).
//   A (W): gload_lds fp32, 16B k-block swizzle kb^=(m&7); frags 2xb128+cvt.
//   B (x): reg-staged transpose -> Bs[px][32k] fp16; 16B slot swizzle
//          slot = ko ^ (px&3) on BOTH ds_write and ds_read; frags 1xb128.
__global__ __launch_bounds__(256, 3) void qkv_gemm_kernel(
    const float* __restrict__ x,
    const float* __restrict__ wq, const float* __restrict__ bq,
    const float* __restrict__ wk, const float* __restrict__ bk,
    const float* __restrict__ wv, const float* __restrict__ bv,
    _Float16* __restrict__ qh, _Float16* __restrict__ kh,
    _Float16* __restrict__ vh)
{
    __shared__ float    As[2][128 * 32];   // 2 x 16 KB fp32
    __shared__ _Float16 Bs[2][128 * 32];   // 2 x  8 KB fp16

    const int t  = threadIdx.x;
    const int bx = blockIdx.x;
    const int u  = (bx & 7) * 96 + (bx >> 3);   // XCD-chunked (768 = 8*96)
    const int mt = u % 6;                       // consecutive u share nt (x panel)
    const int nt = u / 6;                       // 0..127

    const int l     = t & 63;
    const int wid   = t >> 6;
    const int wm    = wid >> 1, wn = wid & 1;
    const int lrow  = l & 15;
    const int grp   = l >> 4;                   // 0..3 (koct)
    const int lrow4 = grp * 4;

    const float* wsel = (mt < 2) ? wq : (mt < 4) ? wk : wv;
    const float* bsel = (mt < 2) ? bq : (mt < 4) ? bk : bv;
    _Float16*    osel = (mt < 2) ? qh : (mt < 4) ? kh : vh;
    const int    mtl  = mt & 1;

    const int bi  = nt >> 5;
    const int px0 = (nt & 31) * 128;

    // acc init with bias
    f32x4 acc[4][4];
    #pragma unroll
    for (int mi = 0; mi < 4; ++mi) {
        const f32x4 bb = *(const f32x4*)&bsel[mtl * 128 + wm * 64 + mi * 16 + lrow4];
        #pragma unroll
        for (int ni = 0; ni < 4; ++ni) acc[mi][ni] = bb;
    }

    // ---- A staging sources (4 x 16B gload_lds per step; swizzled source) ----
    const float* asrc[4];
    #pragma unroll
    for (int i = 0; i < 4; ++i) {
        const int w16 = i * 256 + t;
        const int m  = w16 >> 3;
        const int kb = w16 & 7;
        asrc[i] = wsel + (size_t)(mtl * 128 + m) * CIN + ((kb ^ (m & 7)) * 4);
    }

    // ---- B staging: px = t&127, kocts {t>>7, (t>>7)+2} ----
    const int spx  = t & 127;
    const int sko0 = t >> 7;                 // 0..1
    const float* xbp = x + (size_t)bi * CIN * HWSZ + px0 + spx;
    const int bw0 = spx * 32 + ((sko0       ^ (spx & 3)) * 8);
    const int bw1 = spx * 32 + (((sko0 + 2) ^ (spx & 3)) * 8);

    // ---- prologue: stage kt=0 into buf 0 ----
    {
        #pragma unroll
        for (int i = 0; i < 4; ++i)
            lds_load16(asrc[i], &As[0][(i * 256 + t) * 4]);
        float r0[8], r1[8];
        #pragma unroll
        for (int j = 0; j < 8; ++j) r0[j] = xbp[(size_t)(sko0 * 8 + j) * HWSZ];
        #pragma unroll
        for (int j = 0; j < 8; ++j) r1[j] = xbp[(size_t)((sko0 + 2) * 8 + j) * HWSZ];
        f16x8_t w0, w1;
        #pragma unroll
        for (int j = 0; j < 8; ++j) { w0[j] = (_Float16)r0[j]; w1[j] = (_Float16)r1[j]; }
        *(f16x8_t*)&Bs[0][bw0] = w0;
        *(f16x8_t*)&Bs[0][bw1] = w1;
        __syncthreads();
    }

    for (int kt = 0; kt < 8; ++kt) {
        const int cur = kt & 1, nxt = cur ^ 1;

        // issue next-step loads early (hide under frag reads + MFMA)
        float r0[8], r1[8];
        if (kt < 7) {
            const int kb = (kt + 1) * 32;
            #pragma unroll
            for (int i = 0; i < 4; ++i)
                lds_load16(asrc[i] + kb, &As[nxt][(i * 256 + t) * 4]);
            #pragma unroll
            for (int j = 0; j < 8; ++j) r0[j] = xbp[(size_t)(kb + sko0 * 8 + j) * HWSZ];
            #pragma unroll
            for (int j = 0; j < 8; ++j) r1[j] = xbp[(size_t)(kb + (sko0 + 2) * 8 + j) * HWSZ];
        }

        // A fragments: 2 swizzled b128 fp32 reads + cvt
        f16x8_t af[4];
        #pragma unroll
        for (int mi = 0; mi < 4; ++mi) {
            const int m = wm * 64 + mi * 16 + lrow;
            const int s = m & 7;
            const f32x4 a0 = *(const f32x4*)&As[cur][m * 32 + ((2 * grp) ^ s) * 4];
            const f32x4 a1 = *(const f32x4*)&As[cur][m * 32 + ((2 * grp + 1) ^ s) * 4];
            f16x8_t f;
            #pragma unroll
            for (int j = 0; j < 4; ++j) { f[j] = (_Float16)a0[j]; f[4 + j] = (_Float16)a1[j]; }
            af[mi] = f;
        }
        // B fragments: single swizzled b128 fp16 read
        f16x8_t bf[4];
        #pragma unroll
        for (int ni = 0; ni < 4; ++ni) {
            const int px = wn * 64 + ni * 16 + lrow;
            bf[ni] = *(const f16x8_t*)&Bs[cur][px * 32 + ((grp ^ (px & 3)) * 8)];
        }
        #pragma unroll
        for (int mi = 0; mi < 4; ++mi)
            #pragma unroll
            for (int ni = 0; ni < 4; ++ni)
                acc[mi][ni] = __builtin_amdgcn_mfma_f32_16x16x32_f16(
                    af[mi], bf[ni], acc[mi][ni], 0, 0, 0);

        // write-late: convert + store next B tile
        if (kt < 7) {
            f16x8_t w0, w1;
            #pragma unroll
            for (int j = 0; j < 8; ++j) { w0[j] = (_Float16)r0[j]; w1[j] = (_Float16)r1[j]; }
            *(f16x8_t*)&Bs[nxt][bw0] = w0;
            *(f16x8_t*)&Bs[nxt][bw1] = w1;
        }
        __syncthreads();
    }

    // epilogue: D row (m) = grp*4+reg, col (n) = l&15 — blocked fp16 stores
    #pragma unroll
    for (int ni = 0; ni < 4; ++ni) {
        const size_t ng = (size_t)(nt * 128 + wn * 64 + ni * 16 + lrow);
        #pragma unroll
        for (int mi = 0; mi < 4; ++mi) {
            f16x4_t hv;
            #pragma unroll
            for (int j = 0; j < 4; ++j) hv[j] = (_Float16)acc[mi][ni][j];
            const int chunk = mtl * 8 + wm * 4 + mi;     // 0..15
            *(f16x4_t*)&osel[((size_t)chunk * NTOT + ng) * 16 + lrow4] = hv;
        }
    }
}

// ---------- local grouped attention: q,k,v fp16 blocked; fp32 math ----------
__global__ __launch_bounds__(256) void loc_attn_kernel(
    const _Float16* __restrict__ qh, const _Float16* __restrict__ kh,
    const _Float16* __restrict__ vh, float* __restrict__ out)
{
    const int t   = threadIdx.x;
    const int bx0 = blockIdx.x;
    const int bx  = (bx0 & 7) * 128 + (bx0 >> 3);
    const int h = bx & 63;
    const int g = (bx >> 6) & 3;
    const int b = bx >> 8;

    const int wl  = t & 15;
    const int c   = (t >> 4) & 3;
    const int wid = t >> 6;
    const int w   = wid * 16 + wl;

    const int ck = g * 4 + c;                    // chunk index 0..15
    const size_t n = (size_t)b * HWSZ + h * 64 + w;

    float qf[16];
    {
        const _Float16* qp = &qh[((size_t)ck * NTOT + n) * 16];
        const f16x8_t q0 = *(const f16x8_t*)qp;
        const f16x8_t q1 = *(const f16x8_t*)(qp + 8);
        #pragma unroll
        for (int j = 0; j < 8; ++j) { qf[j] = (float)q0[j]; qf[8 + j] = (float)q1[j]; }
    }

    float logit[9];
    #pragma unroll
    for (int p = 0; p < 9; ++p) {
        const int dh = p / 3 - 1, dw = p % 3 - 1;
        const int hh = h + dh, ww2 = w + dw;
        float part = 0.f;
        if (hh >= 0 && hh < HH && ww2 >= 0 && ww2 < WW) {
            const size_t nn = (size_t)b * HWSZ + hh * 64 + ww2;
            const _Float16* kp = &kh[((size_t)ck * NTOT + nn) * 16];
            const f16x8_t k0 = *(const f16x8_t*)kp;
            const f16x8_t k1 = *(const f16x8_t*)(kp + 8);
            #pragma unroll
            for (int j = 0; j < 8; ++j)
                part += qf[j] * (float)k0[j] + qf[8 + j] * (float)k1[j];
        }
        part += __shfl_xor(part, 16, 64);
        part += __shfl_xor(part, 32, 64);
        logit[p] = part;
    }

    float mx = logit[0];
    #pragma unroll
    for (int p = 1; p < 9; ++p) mx = fmaxf(mx, logit[p]);
    float a[9];
    float s = 0.f;
    #pragma unroll
    for (int p = 0; p < 9; ++p) { a[p] = __expf(logit[p] - mx); s += a[p]; }
    const float inv = 1.f / s;
    #pragma unroll
    for (int p = 0; p < 9; ++p) a[p] *= inv;

    float acc[16];
    #pragma unroll
    for (int dd = 0; dd < 16; ++dd) acc[dd] = 0.f;
    #pragma unroll
    for (int p = 0; p < 9; ++p) {
        const int dh = p / 3 - 1, dw = p % 3 - 1;
        const int hh = h + dh, ww2 = w + dw;
        if (hh < 0 || hh >= HH || ww2 < 0 || ww2 >= WW) continue;
        const size_t nn = (size_t)b * HWSZ + hh * 64 + ww2;
        const _Float16* vp = &vh[((size_t)ck * NTOT + nn) * 16];
        const f16x8_t v0 = *(const f16x8_t*)vp;
        const f16x8_t v1 = *(const f16x8_t*)(vp + 8);
        const float ap = a[p];
        #pragma unroll
        for (int j = 0; j < 8; ++j) {
            acc[j]     += ap * (float)v0[j];
            acc[8 + j] += ap * (float)v1[j];
        }
    }

    const int obase = b * 256 + g * 64 + c * 16;
    const int off = h * 64 + w;
    #pragma unroll
    for (int dd = 0; dd < 16; ++dd)
        out[(size_t)(obase + dd) * HWSZ + off] = acc[dd];
}

extern "C" void kernel_launch(void* const* d_in, const int* in_sizes, int n_in,
                              void* d_out, int out_size, void* d_ws, size_t ws_size,
                              hipStream_t stream) {
    const float* x  = (const float*)d_in[0];
    const float* wq = (const float*)d_in[1];
    const float* bq = (const float*)d_in[2];
    const float* wk = (const float*)d_in[3];
    const float* bk = (const float*)d_in[4];
    const float* wv = (const float*)d_in[5];
    const float* bv = (const float*)d_in[6];
    float* out = (float*)d_out;

    char* ws = (char*)d_ws;
    _Float16* qh = (_Float16*)ws;                      //  8.39 MB
    _Float16* kh = (_Float16*)(ws + 8388608);          //  8.39 MB
    _Float16* vh = (_Float16*)(ws + 16777216);         //  8.39 MB

    qkv_gemm_kernel<<<dim3(768), 256, 0, stream>>>(x, wq, bq, wk, bk, wv, bv,
                                                   qh, kh, vh);
    loc_attn_kernel<<<dim3(1024), 256, 0, stream>>>(qh, kh, vh, out);
}